// Round 1
// baseline (169.495 us; speedup 1.0000x reference)
//
#include <hip/hip_runtime.h>
#include <hip/hip_bf16.h>

typedef unsigned short ushort_t;
typedef __attribute__((ext_vector_type(8))) short short8;
typedef __attribute__((ext_vector_type(8))) unsigned short u16x8;
typedef __attribute__((ext_vector_type(4))) float f32x4;

#define BETA 0.4f
#define EPS_C 0.05f
#define NB 8192
#define NH 1024
#define NL 2048
#define NC 5

static __device__ __forceinline__ float b2f(unsigned short u) {
    union { unsigned int i; float f; } x; x.i = ((unsigned int)u) << 16; return x.f;
}
static __device__ __forceinline__ unsigned short f2b(float f) {
    union { float f; unsigned int i; } x; x.f = f;
    unsigned int i = x.i;
    unsigned int r = (i + 0x7FFFu + ((i >> 16) & 1u)) >> 16;
    return (unsigned short)r;
}

static __device__ __forceinline__ void gload16(const void* g, void* l) {
    __builtin_amdgcn_global_load_lds((const __attribute__((address_space(1))) void*)g,
                                     (__attribute__((address_space(3))) void*)l, 16, 0, 0);
}

// ---------------- conversion kernels ----------------
__global__ __launch_bounds__(256) void cvt_kernel(const float* __restrict__ in,
                                                  ushort_t* __restrict__ out, long n) {
    long i = ((long)blockIdx.x * 256 + threadIdx.x) * 8;
    if (i >= n) return;
    const float4 a = *(const float4*)(in + i);
    const float4 b = *(const float4*)(in + i + 4);
    u16x8 o;
    o[0] = f2b(a.x); o[1] = f2b(a.y); o[2] = f2b(a.z); o[3] = f2b(a.w);
    o[4] = f2b(b.x); o[5] = f2b(b.y); o[6] = f2b(b.z); o[7] = f2b(b.w);
    *(u16x8*)(out + i) = o;
}

// W1 [2048,1024] -> W1T bf16 [1024,2048]
__global__ __launch_bounds__(256) void trans_kernel(const float* __restrict__ W1,
                                                    ushort_t* __restrict__ W1Tb) {
    __shared__ float tile[32][33];
    const int tx = threadIdx.x & 31, ty = threadIdx.x >> 5;
    const int k0 = blockIdx.x * 32, n0 = blockIdx.y * 32;
#pragma unroll
    for (int i = 0; i < 4; ++i)
        tile[ty + i * 8][tx] = W1[(size_t)(k0 + ty + i * 8) * NH + n0 + tx];
    __syncthreads();
#pragma unroll
    for (int i = 0; i < 4; ++i)
        W1Tb[(size_t)(n0 + ty + i * 8) * NL + k0 + tx] = f2b(tile[tx][ty + i * 8]);
}

// ---------------- GEMM (C = A @ Bt^T), A [M,K] bf16, Bt [N,K] bf16 ----------------
// EPI 0: h = tanh(acc + b1[col]) -> hout bf16 [M,N]
// EPI 1: per-row sum |acc| partials -> partout[blockIdx.y*M + row]
#define BM 128
#define BN 128
#define BK 32

template <int EPI>
__global__ __launch_bounds__(256) void gemm_bt(const ushort_t* __restrict__ A,
                                               const ushort_t* __restrict__ Bt,
                                               int M, int N, int K, int lda, int ldb,
                                               const float* __restrict__ b1,
                                               ushort_t* __restrict__ hout,
                                               float* __restrict__ partout) {
    __shared__ ushort_t As[BM * BK];
    __shared__ ushort_t Bs[BN * BK];
    __shared__ float rsum[2][BM];

    const int tid = threadIdx.x;
    const int wid = tid >> 6;
    const int lane = tid & 63;
    const int wm = wid >> 1, wn = wid & 1;
    const int bm0 = blockIdx.x * BM, bn0 = blockIdx.y * BN;

    f32x4 acc[4][4] = {};

    const int crow = lane >> 2;
    const int ccol = (lane & 3) * 8;
    const int fr = lane & 15;
    const int fg = lane >> 4;
    const int fc = fg * 8;

    for (int k0 = 0; k0 < K; k0 += BK) {
#pragma unroll
        for (int i = 0; i < 2; ++i) {
            int c = wid * 2 + i;
            int arow = c * 16 + crow;
            gload16(A + (size_t)(bm0 + arow) * lda + k0 + ccol, &As[c * 512]);
            gload16(Bt + (size_t)(bn0 + arow) * ldb + k0 + ccol, &Bs[c * 512]);
        }
        __syncthreads();
        short8 af[4], bfr[4];
#pragma unroll
        for (int m = 0; m < 4; ++m)
            af[m] = *(const short8*)&As[(wm * 64 + m * 16 + fr) * BK + fc];
#pragma unroll
        for (int n = 0; n < 4; ++n)
            bfr[n] = *(const short8*)&Bs[(wn * 64 + n * 16 + fr) * BK + fc];
#pragma unroll
        for (int m = 0; m < 4; ++m)
#pragma unroll
            for (int n = 0; n < 4; ++n)
                acc[m][n] = __builtin_amdgcn_mfma_f32_16x16x32_bf16(af[m], bfr[n], acc[m][n], 0, 0, 0);
        __syncthreads();
    }

    if (EPI == 0) {
#pragma unroll
        for (int m = 0; m < 4; ++m) {
#pragma unroll
            for (int n = 0; n < 4; ++n) {
                int col = bn0 + wn * 64 + n * 16 + fr;
                float bb = b1[col];
#pragma unroll
                for (int r = 0; r < 4; ++r) {
                    int row = bm0 + wm * 64 + m * 16 + fg * 4 + r;
                    hout[(size_t)row * N + col] = f2b(tanhf(acc[m][n][r] + bb));
                }
            }
        }
    } else {
#pragma unroll
        for (int m = 0; m < 4; ++m) {
#pragma unroll
            for (int r = 0; r < 4; ++r) {
                float s = 0.f;
#pragma unroll
                for (int n = 0; n < 4; ++n) s += fabsf(acc[m][n][r]);
                s += __shfl_xor(s, 1);
                s += __shfl_xor(s, 2);
                s += __shfl_xor(s, 4);
                s += __shfl_xor(s, 8);
                if ((lane & 15) == 0) rsum[wn][wm * 64 + m * 16 + fg * 4 + r] = s;
            }
        }
        __syncthreads();
        if (tid < BM) {
            partout[(size_t)blockIdx.y * M + bm0 + tid] = rsum[0][tid] + rsum[1][tid];
        }
    }
}

// ---------------- per-row kernel: logits, losses, v ----------------
__global__ __launch_bounds__(256) void rows_kernel(const ushort_t* __restrict__ hb,
                                                   const int* __restrict__ y,
                                                   const float* __restrict__ W2,
                                                   const float* __restrict__ b2,
                                                   ushort_t* __restrict__ vb,
                                                   float4* __restrict__ rowstats) {
    __shared__ float w2s[NH * NC];
    __shared__ float b2s[NC];
    const int tid = threadIdx.x;
    for (int i = tid; i < NH * NC; i += 256) w2s[i] = W2[i];
    if (tid < NC) b2s[tid] = b2[tid];
    __syncthreads();
    const int wid = tid >> 6, lane = tid & 63;
    const int row = blockIdx.x * 4 + wid;
    const ushort_t* hrow = hb + (size_t)row * NH;
    ushort_t* vrow = vb + (size_t)row * NH;
    const int yi = y[row];
    float d0 = 0, d1 = 0, d2 = 0, d3 = 0, d4 = 0;
#pragma unroll
    for (int it = 0; it < 2; ++it) {
        const int n0 = it * 512 + lane * 8;
        u16x8 hv = *(const u16x8*)(hrow + n0);
        u16x8 ov;
#pragma unroll
        for (int j = 0; j < 8; ++j) {
            float hh = b2f(hv[j]);
            const float* wrow = &w2s[(n0 + j) * NC];
            d0 += hh * wrow[0]; d1 += hh * wrow[1]; d2 += hh * wrow[2];
            d3 += hh * wrow[3]; d4 += hh * wrow[4];
            ov[j] = f2b((1.f - hh * hh) * wrow[yi]);
        }
        *(u16x8*)(vrow + n0) = ov;
    }
#pragma unroll
    for (int off = 32; off; off >>= 1) {
        d0 += __shfl_xor(d0, off); d1 += __shfl_xor(d1, off); d2 += __shfl_xor(d2, off);
        d3 += __shfl_xor(d3, off); d4 += __shfl_xor(d4, off);
    }
    if (lane == 0) {
        float lg[NC] = { d0 + b2s[0], d1 + b2s[1], d2 + b2s[2], d3 + b2s[3], d4 + b2s[4] };
        float zy = lg[yi];
        float mse = 0.f, marg = 0.f;
        int amax = 0; float best = lg[0];
#pragma unroll
        for (int c = 0; c < NC; ++c) {
            float t = lg[c] - (c == yi ? 1.f : 0.f);
            mse += t * t;
            if (c != yi) marg += fmaxf(1.f - zy + lg[c], 0.f);
            if (lg[c] > best) { best = lg[c]; amax = c; }
        }
        rowstats[row] = make_float4(zy, mse, marg, (amax == yi) ? 1.f : 0.f);
    }
}

// ---------------- reductions ----------------
__global__ __launch_bounds__(256) void reduce_rows(const float4* __restrict__ rs,
                                                   const float* __restrict__ part,
                                                   int NT, float4* __restrict__ bsums) {
    const int tid = threadIdx.x;
    const int r = blockIdx.x * 256 + tid;
    float4 v = rs[r];
    float wl1 = 0.f;
    for (int t = 0; t < NT; ++t) wl1 += part[(size_t)t * NB + r];
    float R = wl1 * EPS_C / (fabsf(v.x) + 1e-8f);
    float4 s = make_float4(v.y, v.z, v.w, log1pf(R));
#pragma unroll
    for (int off = 32; off; off >>= 1) {
        s.x += __shfl_down(s.x, off); s.y += __shfl_down(s.y, off);
        s.z += __shfl_down(s.z, off); s.w += __shfl_down(s.w, off);
    }
    __shared__ float4 red[4];
    if ((tid & 63) == 0) red[tid >> 6] = s;
    __syncthreads();
    if (tid == 0) {
        float4 t = red[0];
        for (int i = 1; i < 4; ++i) { t.x += red[i].x; t.y += red[i].y; t.z += red[i].z; t.w += red[i].w; }
        bsums[blockIdx.x] = t;
    }
}

__global__ void final_combine(const float4* __restrict__ bsums, int nb, float* __restrict__ out) {
    if (threadIdx.x == 0) {
        float mse = 0, marg = 0, corr = 0, nsr = 0;
        for (int i = 0; i < nb; ++i) {
            float4 s = bsums[i];
            mse += s.x; marg += s.y; corr += s.z; nsr += s.w;
        }
        const float Bf = (float)NB;
        out[0] = mse / (Bf * (float)NC) + (marg / Bf + BETA * nsr / Bf) * (corr / Bf);
    }
}

extern "C" void kernel_launch(void* const* d_in, const int* in_sizes, int n_in,
                              void* d_out, int out_size, void* d_ws, size_t ws_size,
                              hipStream_t stream) {
    const float* x  = (const float*)d_in[0];
    const int*   y  = (const int*)d_in[1];
    const float* W1 = (const float*)d_in[2];
    const float* b1 = (const float*)d_in[3];
    const float* W2 = (const float*)d_in[4];
    const float* b2 = (const float*)d_in[5];
    float* out = (float*)d_out;

    char* ws = (char*)d_ws;
    ushort_t* W1Tb = (ushort_t*)(ws);                          // 1024*2048*2 = 4MB
    ushort_t* W1b  = (ushort_t*)(ws + (4ul << 20));            // 4MB
    ushort_t* xb   = (ushort_t*)(ws + (8ul << 20));            // 32MB
    ushort_t* hb   = (ushort_t*)(ws + (40ul << 20));           // 16MB
    ushort_t* vb   = (ushort_t*)(ws + (56ul << 20));           // 16MB
    float4*   rowstats = (float4*)(ws + (72ul << 20));         // 128KB
    float*    part = (float*)(ws + (72ul << 20) + (1ul << 20)); // 512KB
    float4*   bsums = (float4*)(ws + (74ul << 20));            // 512B

    // 1. conversions
    cvt_kernel<<<(NB * (long)NL) / (256 * 8), 256, 0, stream>>>(x, xb, (long)NB * NL);
    cvt_kernel<<<(NL * (long)NH) / (256 * 8), 256, 0, stream>>>(W1, W1b, (long)NL * NH);
    trans_kernel<<<dim3(NL / 32, NH / 32), 256, 0, stream>>>(W1, W1Tb);

    // 2. GEMM1: h = tanh(x @ W1 + b1)   M=8192 N=1024 K=2048
    gemm_bt<0><<<dim3(NB / BM, NH / BN), 256, 0, stream>>>(xb, W1Tb, NB, NH, NL, NL, NL, b1, hb, nullptr);

    // 3. per-row: logits/mse/margin/zy/correct + v
    rows_kernel<<<NB / 4, 256, 0, stream>>>(hb, y, W2, b2, vb, rowstats);

    // 4. GEMM2: g = v @ W1^T, row-wise |.| partials   M=8192 N=2048 K=1024
    gemm_bt<1><<<dim3(NB / BM, NL / BN), 256, 0, stream>>>(vb, W1b, NB, NL, NH, NH, NH, nullptr, nullptr, part);

    // 5. reductions
    reduce_rows<<<NB / 256, 256, 0, stream>>>(rowstats, part, NL / BN, bsums);
    final_combine<<<1, 64, 0, stream>>>(bsums, NB / 256, out);
}